// Round 13
// baseline (1597.597 us; speedup 1.0000x reference)
//
#include <hip/hip_runtime.h>
#include <hip/hip_fp16.h>
#include <cstdint>
#include <cstddef>

#define TTOK 8192
#define HD   2048
#define ID   4096
#define NE   8
#define NPAIR (TTOK * 2)            // 16384 routed pairs
#define PADROWS 18432               // 16384 + 8*256 worst-case padded rows
#define RBMAX 72                    // PADROWS / 256
#define WS_SLAB ((size_t)2 * ID * HD)   // elems per expert in Ws

typedef _Float16 h8 __attribute__((ext_vector_type(8)));
typedef float    f4 __attribute__((ext_vector_type(4)));

#define VMWAIT(n) asm volatile("s_waitcnt vmcnt(" #n ")" ::: "memory")
#define MEMFENCE  asm volatile("" ::: "memory")
#define BAR()     __builtin_amdgcn_s_barrier()

__device__ __forceinline__ void async_cp16(const void* g, void* l) {
  __builtin_amdgcn_global_load_lds(
      (const __attribute__((address_space(1))) unsigned int*)g,
      (__attribute__((address_space(3))) unsigned int*)l, 16, 0, 0);
}

__device__ __forceinline__ f4 zero4() { f4 z = {0.f, 0.f, 0.f, 0.f}; return z; }

// ---- contiguous fp32->f16 slice cvt (512-thread blocks, grid-stride cb/ncb) ----
__device__ __forceinline__ void cvt_slice(const float* __restrict__ src,
                                          _Float16* __restrict__ dst,
                                          size_t base, size_t n, int cb, int ncb) {
  size_t stride = (size_t)ncb * 512 * 8;
  for (size_t i = ((size_t)cb * 512 + threadIdx.x) * 8; i < n; i += stride) {
    const float4* s = (const float4*)(src + base + i);
    float4 a = s[0], b = s[1];
    h8 o;
    o[0] = (_Float16)a.x; o[1] = (_Float16)a.y; o[2] = (_Float16)a.z; o[3] = (_Float16)a.w;
    o[4] = (_Float16)b.x; o[5] = (_Float16)b.y; o[6] = (_Float16)b.z; o[7] = (_Float16)b.w;
    *(h8*)(dst + base + i) = o;
  }
}

// ---- W2 K-half cvt: w2f[e][h][kh*2048 + ic] -> dst[(e*HD+h)*2048 + ic]
__device__ __forceinline__ void cvt_w2_half(const float* __restrict__ w2f,
                                            _Float16* __restrict__ dst,
                                            int kh, int cb, int ncb) {
  const size_t n = (size_t)NE * HD * 2048;
  size_t stride = (size_t)ncb * 512 * 8;
  for (size_t j = ((size_t)cb * 512 + threadIdx.x) * 8; j < n; j += stride) {
    size_t row = j >> 11, ic = j & 2047;
    const float4* s = (const float4*)(w2f + row * ID + (size_t)kh * 2048 + ic);
    float4 a = s[0], b = s[1];
    h8 o;
    o[0] = (_Float16)a.x; o[1] = (_Float16)a.y; o[2] = (_Float16)a.z; o[3] = (_Float16)a.w;
    o[4] = (_Float16)b.x; o[5] = (_Float16)b.y; o[6] = (_Float16)b.z; o[7] = (_Float16)b.w;
    *(h8*)(dst + row * 2048 + ic) = o;
  }
}

// ---- pre-pass: convert Ws for experts 0-1 only (~80 us) ----
__global__ __launch_bounds__(512) void cvt_ws01_kernel(
    const float* __restrict__ wsf, _Float16* __restrict__ wsh) {
  cvt_slice(wsf, wsh, 0, 2 * WS_SLAB, blockIdx.x, gridDim.x);
}

// ---------------- gate: wave per token, 8 dots, top-2; also emits xh = f16(x) ----
__global__ __launch_bounds__(256) void gate_kernel(
    const float* __restrict__ x, const float* __restrict__ gw,
    int* __restrict__ counts, int* __restrict__ tids, float* __restrict__ tw,
    _Float16* __restrict__ xh) {
  int lane = threadIdx.x & 63;
  int t = blockIdx.x * 4 + (threadIdx.x >> 6);
  const float* xr = x + (size_t)t * HD;
  _Float16* xhr = xh + (size_t)t * HD;
  float acc[NE];
#pragma unroll
  for (int e = 0; e < NE; e++) acc[e] = 0.f;
  for (int j = lane; j < HD; j += 64) {
    float xv = xr[j];
    xhr[j] = (_Float16)xv;            // fused x -> f16
#pragma unroll
    for (int e = 0; e < NE; e++) acc[e] += xv * gw[e * HD + j];
  }
#pragma unroll
  for (int off = 32; off > 0; off >>= 1) {
#pragma unroll
    for (int e = 0; e < NE; e++) acc[e] += __shfl_xor(acc[e], off, 64);
  }
  if (lane == 0) {
    int e0 = 0; float v0 = acc[0];
#pragma unroll
    for (int e = 1; e < NE; e++) if (acc[e] > v0) { v0 = acc[e]; e0 = e; }
    int e1 = -1; float v1 = -1e30f;
#pragma unroll
    for (int e = 0; e < NE; e++) if (e != e0 && acc[e] > v1) { v1 = acc[e]; e1 = e; }
    float b = __expf(v1 - v0);
    float w0 = 1.f / (1.f + b);
    tids[2 * t] = e0; tids[2 * t + 1] = e1;
    tw[2 * t] = w0;   tw[2 * t + 1] = b * w0;
    atomicAdd(&counts[e0], 1); atomicAdd(&counts[e1], 1);
  }
}

// ---------------- scan: per-expert 256-padded offsets ----------------
__global__ void scan_kernel(const int* __restrict__ counts, int* __restrict__ offs,
                            int* __restrict__ cursor) {
  if (threadIdx.x == 0 && blockIdx.x == 0) {
    int off = 0;
    for (int e = 0; e < NE; e++) {
      offs[e] = off; cursor[e] = off;
      off += ((counts[e] + 255) >> 8) << 8;
    }
    offs[NE] = off;
  }
}

// ---------------- scatter tokens (records token->slot map) ----------------
__global__ void scatter_kernel(const int* __restrict__ tids, const float* __restrict__ tw,
                               int* __restrict__ cursor, int* __restrict__ perm,
                               float* __restrict__ pw, int* __restrict__ pairpos) {
  int t = blockIdx.x * 256 + threadIdx.x;
#pragma unroll
  for (int k = 0; k < 2; k++) {
    int e = tids[2 * t + k];
    int pos = atomicAdd(&cursor[e], 1);
    perm[pos] = t; pw[pos] = tw[2 * t + k];
    pairpos[2 * t + k] = pos;
  }
}

// ---------------- mark padding ----------------
__global__ void padfill_kernel(const int* __restrict__ counts, const int* __restrict__ offs,
                               int* __restrict__ perm) {
  int s = blockIdx.x * 256 + threadIdx.x;
#pragma unroll
  for (int e = 0; e < NE; e++) {
    if (s >= offs[e] + counts[e] && s < offs[e + 1]) perm[s] = -1;
  }
}

// ============================================================================
// r7's PROVEN 8-phase 256x256x64 KLOOP — UNTOUCHED.
// ============================================================================
#define LA(BB, H) ((BB) * 65536 + (H) * 16384)
#define LB(BB, H) ((BB) * 65536 + 32768 + (H) * 16384)
#define RD(boff) (*(const h8*)(smem + (boff)))

#define LOAD_AF(BB, MH) do { \
  af[0][0] = RD(LA(BB,MH) + amoff + 0*2048 + sa0); \
  af[0][1] = RD(LA(BB,MH) + amoff + 0*2048 + sa1); \
  af[1][0] = RD(LA(BB,MH) + amoff + 1*2048 + sa0); \
  af[1][1] = RD(LA(BB,MH) + amoff + 1*2048 + sa1); \
  af[2][0] = RD(LA(BB,MH) + amoff + 2*2048 + sa0); \
  af[2][1] = RD(LA(BB,MH) + amoff + 2*2048 + sa1); \
  af[3][0] = RD(LA(BB,MH) + amoff + 3*2048 + sa0); \
  af[3][1] = RD(LA(BB,MH) + amoff + 3*2048 + sa1); } while (0)

#define LOAD_BFG(BB) do { \
  bfg[0][0] = RD(LB(BB,0) + bnoff + 0*2048 + sa0); \
  bfg[0][1] = RD(LB(BB,0) + bnoff + 0*2048 + sa1); \
  bfg[1][0] = RD(LB(BB,0) + bnoff + 1*2048 + sa0); \
  bfg[1][1] = RD(LB(BB,0) + bnoff + 1*2048 + sa1); } while (0)

#define LOAD_BFU(BB) do { \
  bfu[0][0] = RD(LB(BB,1) + bnoff + 0*2048 + sa0); \
  bfu[0][1] = RD(LB(BB,1) + bnoff + 0*2048 + sa1); \
  bfu[1][0] = RD(LB(BB,1) + bnoff + 1*2048 + sa0); \
  bfu[1][1] = RD(LB(BB,1) + bnoff + 1*2048 + sa1); } while (0)

#define MM(MH,NH,BF,M,N) \
  acc[MH][NH][M][N] = __builtin_amdgcn_mfma_f32_16x16x32_f16(af[M][0], BF[N][0], acc[MH][NH][M][N], 0, 0, 0); \
  acc[MH][NH][M][N] = __builtin_amdgcn_mfma_f32_16x16x32_f16(af[M][1], BF[N][1], acc[MH][NH][M][N], 0, 0, 0);

#define MFMAQ(MH,NH,BF) do { __builtin_amdgcn_s_setprio(1); \
  MM(MH,NH,BF,0,0) MM(MH,NH,BF,0,1) MM(MH,NH,BF,1,0) MM(MH,NH,BF,1,1) \
  MM(MH,NH,BF,2,0) MM(MH,NH,BF,2,1) MM(MH,NH,BF,3,0) MM(MH,NH,BF,3,1) \
  __builtin_amdgcn_s_setprio(0); } while (0)

#define STG(gp, ldsbyte, kt) do { \
  async_cp16(gp[0] + (size_t)(kt) * 64, smem + (ldsbyte) + (wid * 2 + 0) * 1024 + lane * 16); \
  async_cp16(gp[1] + (size_t)(kt) * 64, smem + (ldsbyte) + (wid * 2 + 1) * 1024 + lane * 16); } while (0)

#define ACC_ZERO() do { \
  _Pragma("unroll") for (int mh = 0; mh < 2; mh++) \
  _Pragma("unroll") for (int nh = 0; nh < 2; nh++) \
  _Pragma("unroll") for (int m = 0; m < 4; m++) \
  _Pragma("unroll") for (int n = 0; n < 2; n++) acc[mh][nh][m][n] = zero4(); } while (0)

#define KLOOP(NI) \
  STG(gA[0], LA(0,0), 0); STG(gA[1], LA(0,1), 0); \
  STG(gB[0], LB(0,0), 0); STG(gB[1], LB(0,1), 0); \
  STG(gA[0], LA(1,0), 1); STG(gB[1], LB(1,1), 1); \
  VMWAIT(4); \
  BAR(); \
  for (int i = 0; i < (NI); ++i) { \
    bool last = (i == (NI) - 1); \
    int kt1 = 2 * i + 1, kt2 = 2 * i + 2, kt3 = 2 * i + 3; \
    /* ph1 */ \
    MEMFENCE; LOAD_AF(0,0); LOAD_BFG(0); \
    STG(gA[1], LA(1,1), kt1); STG(gB[0], LB(1,0), kt1); \
    BAR(); MEMFENCE; MFMAQ(0,0,bfg); BAR(); \
    /* ph2 */ \
    MEMFENCE; LOAD_BFU(0); \
    BAR(); MEMFENCE; MFMAQ(0,1,bfu); BAR(); \
    /* ph3 */ \
    MEMFENCE; LOAD_AF(0,1); \
    if (!last) STG(gA[0], LA(0,0), kt2); \
    BAR(); MEMFENCE; MFMAQ(1,1,bfu); BAR(); \
    /* ph4 (no ds_reads: bfg retained from ph1) */ \
    MEMFENCE; \
    if (!last) { STG(gB[1], LB(0,1), kt2); VMWAIT(4); } else { VMWAIT(0); } \
    BAR(); MEMFENCE; MFMAQ(1,0,bfg); BAR(); \
    /* ph5 */ \
    MEMFENCE; LOAD_AF(1,0); LOAD_BFG(1); \
    if (!last) { STG(gA[1], LA(0,1), kt2); STG(gB[0], LB(0,0), kt2); } \
    BAR(); MEMFENCE; MFMAQ(0,0,bfg); BAR(); \
    /* ph6 */ \
    MEMFENCE; LOAD_BFU(1); \
    BAR(); MEMFENCE; MFMAQ(0,1,bfu); BAR(); \
    /* ph7 */ \
    MEMFENCE; LOAD_AF(1,1); \
    if (!last) STG(gA[0], LA(1,0), kt3); \
    BAR(); MEMFENCE; MFMAQ(1,1,bfu); BAR(); \
    /* ph8 (no ds_reads) */ \
    MEMFENCE; \
    if (!last) { STG(gB[1], LB(1,1), kt3); VMWAIT(4); } \
    BAR(); MEMFENCE; MFMAQ(1,0,bfg); BAR(); \
  }

// expert lookup from 256-aligned offsets (row0 = global row-block * 256)
__device__ __forceinline__ int expert_of(const int* offs, int row0) {
  int e = 0;
#pragma unroll
  for (int k = 1; k < NE; k++) if (offs[k] <= row0) e = k;
  return e;
}

// ---- gemm1 (pair dispatch pid=0..3, experts {2p,2p+1}); y==0 = 32 cvt blocks
//      (dispatched first, run concurrently on ~32 CUs using spare BW):
//        pid<3: convert Ws slabs {2p+2, 2p+3} (consumed by NEXT dispatch)
//        pid 0/1: + half of w2h0;   pid 2/3: + half of w2h1 (w2h1 region =
//        Ws slabs 0-1, read only by dispatches 0-1 -> disjoint for pid>=2)
//      y=1..RBMAX: gemm row-blocks (gyy = y-1 covers 0..71 — r12 bug fixed)
__global__ __launch_bounds__(512, 2) void gemm1_kernel(
    const _Float16* __restrict__ xh, const _Float16* __restrict__ wsh,
    const int* __restrict__ offs, const int* __restrict__ perm,
    _Float16* __restrict__ hb,
    const float* __restrict__ wsf, const float* __restrict__ w2f,
    _Float16* __restrict__ w2h0, _Float16* __restrict__ w2h1, int pid) {
  if (blockIdx.y == 0) {               // cvt row: 32 blocks, dispatched first
    int tb = blockIdx.x;               // 0..31
    if (pid < 3)
      cvt_slice(wsf, (_Float16*)wsh, (size_t)(2 * pid + 2) * WS_SLAB, 2 * WS_SLAB, tb, 32);
    if (pid < 2) cvt_w2_half(w2f, w2h0, 0, pid * 32 + tb, 64);
    else         cvt_w2_half(w2f, w2h1, 1, (pid - 2) * 32 + tb, 64);
    return;
  }
  int bx = blockIdx.x, gyy = blockIdx.y - 1;   // global row-block 0..RBMAX-1
  int row0 = gyy << 8;
  if (row0 < offs[2 * pid] || row0 >= offs[2 * pid + 2]) return;
  int e = expert_of(offs, row0);
  int n0 = bx << 7;   // 128 h-cols

  __shared__ char smem[131072];
  int tid = threadIdx.x, lane = tid & 63, wid = tid >> 6;
  int wm = wid >> 2, wn = wid & 3;
  int lr = lane & 15, ks = lane >> 4;
  int sa0 = lr * 128 + (((ks)     ^ (lr & 7)) << 4);
  int sa1 = lr * 128 + (((ks + 4) ^ (lr & 7)) << 4);
  int amoff = wm * 8192;
  int bnoff = wn * 4096;

  int srow = wid * 16 + (lane >> 3);
  int scol = ((lane & 7) ^ (lane >> 3)) * 8;   // pre-swizzled source chunk
  const _Float16* gA[2][2]; const _Float16* gB[2][2];
#pragma unroll
  for (int h = 0; h < 2; h++)
#pragma unroll
    for (int j = 0; j < 2; j++) {
      int r = row0 + h * 128 + srow + j * 8;
      int pv = perm[r]; if (pv < 0) pv = 0;
      gA[h][j] = xh + (size_t)pv * HD + scol;
      gB[h][j] = wsh + ((size_t)e * 2 * ID + (size_t)h * ID + n0 + srow + j * 8) * HD + scol;
    }

  f4 acc[2][2][4][2];
  h8 af[4][2], bfg[2][2], bfu[2][2];
  ACC_ZERO();

  KLOOP(16)   // HD / 128

  // epilogue: silu(g)*u fused in-register (nh0 = g, nh1 = u, same h-col)
#pragma unroll
  for (int mh = 0; mh < 2; mh++)
#pragma unroll
    for (int m = 0; m < 4; m++)
#pragma unroll
      for (int n = 0; n < 2; n++)
#pragma unroll
        for (int r = 0; r < 4; r++) {
          float g = acc[mh][0][m][n][r], u = acc[mh][1][m][n][r];
          float hv = g / (1.f + __expf(-g)) * u;
          int row = row0 + mh * 128 + wm * 64 + m * 16 + ks * 4 + r;
          int col = n0 + wn * 32 + n * 16 + lr;
          __builtin_nontemporal_store((_Float16)hv, hb + (size_t)row * ID + col);
        }
}

// ---- gemm2 (K-split, z=2 single dispatch): hb2[kh] = h[:,kh-half] @ W2half^T ----
__global__ __launch_bounds__(512, 2) void gemm2_kernel(
    const _Float16* __restrict__ hb, const _Float16* __restrict__ w2h0,
    const _Float16* __restrict__ w2h1, const int* __restrict__ offs,
    _Float16* __restrict__ hb2) {
  int bx = blockIdx.x, gyy = blockIdx.y;
  int row0 = gyy << 8;
  if (row0 >= offs[NE]) return;
  int e = expert_of(offs, row0);
  int n0 = bx << 8;                  // 256 out-cols
  int kh = blockIdx.z;               // K half
  const _Float16* w2hk = kh ? w2h1 : w2h0;
  size_t k0 = (size_t)kh * 2048;

  __shared__ char smem[131072];
  int tid = threadIdx.x, lane = tid & 63, wid = tid >> 6;
  int wm = wid >> 2, wn = wid & 3;
  int lr = lane & 15, ks = lane >> 4;
  int sa0 = lr * 128 + (((ks)     ^ (lr & 7)) << 4);
  int sa1 = lr * 128 + (((ks + 4) ^ (lr & 7)) << 4);
  int amoff = wm * 8192;
  int bnoff = wn * 4096;

  int srow = wid * 16 + (lane >> 3);
  int scol = ((lane & 7) ^ (lane >> 3)) * 8;
  const _Float16* gA[2][2]; const _Float16* gB[2][2];
#pragma unroll
  for (int h = 0; h < 2; h++)
#pragma unroll
    for (int j = 0; j < 2; j++) {
      gA[h][j] = hb + ((size_t)(row0 + h * 128 + srow + j * 8)) * ID + k0 + scol;
      gB[h][j] = w2hk + ((size_t)e * HD + n0 + h * 128 + srow + j * 8) * 2048 + scol;
    }

  f4 acc[2][2][4][2];
  h8 af[4][2], bfg[2][2], bfu[2][2];
  ACC_ZERO();

  KLOOP(16)   // 2048 / 128

#pragma unroll
  for (int mh = 0; mh < 2; mh++)
#pragma unroll
    for (int nh = 0; nh < 2; nh++)
#pragma unroll
      for (int m = 0; m < 4; m++)
#pragma unroll
        for (int n = 0; n < 2; n++)
#pragma unroll
          for (int r = 0; r < 4; r++) {
            int row = row0 + mh * 128 + wm * 64 + m * 16 + ks * 4 + r;
            int col = n0 + nh * 128 + wn * 32 + n * 16 + lr;
            hb2[(size_t)kh * PADROWS * HD + (size_t)row * HD + col] =
                (_Float16)acc[mh][nh][m][n][r];
          }
}

// ---- combine: out[t] = pw[p0]*(A0+A1)[p0] + pw[p1]*(B0+B1)[p1], fixed order ----
__global__ __launch_bounds__(256) void combine_kernel(
    const _Float16* __restrict__ hb2, const int* __restrict__ pairpos,
    const float* __restrict__ pw, float* __restrict__ out) {
  int i = blockIdx.x * 256 + threadIdx.x;   // T*HD/8 threads
  int t = i >> 8, g = (i & 255) * 8;
  int p0 = pairpos[2 * t], p1 = pairpos[2 * t + 1];
  float w0 = pw[p0], w1 = pw[p1];
  const _Float16* hb2b = hb2 + (size_t)PADROWS * HD;
  h8 a0 = *(const h8*)(hb2  + (size_t)p0 * HD + g);
  h8 a1 = *(const h8*)(hb2b + (size_t)p0 * HD + g);
  h8 b0 = *(const h8*)(hb2  + (size_t)p1 * HD + g);
  h8 b1 = *(const h8*)(hb2b + (size_t)p1 * HD + g);
  f4 o0, o1;
#pragma unroll
  for (int j = 0; j < 4; j++)
    o0[j] = w0 * ((float)a0[j] + (float)a1[j]) + w1 * ((float)b0[j] + (float)b1[j]);
#pragma unroll
  for (int j = 0; j < 4; j++)
    o1[j] = w0 * ((float)a0[j + 4] + (float)a1[j + 4]) + w1 * ((float)b0[j + 4] + (float)b1[j + 4]);
  __builtin_nontemporal_store(o0, (f4*)(out + (size_t)t * HD + g));
  __builtin_nontemporal_store(o1, (f4*)(out + (size_t)t * HD + g + 4));
}

// ---------------- host launcher ----------------
extern "C" void kernel_launch(void* const* d_in, const int* in_sizes, int n_in,
                              void* d_out, int out_size, void* d_ws, size_t ws_size,
                              hipStream_t stream) {
  const float* x   = (const float*)d_in[0];
  const float* gw  = (const float*)d_in[1];
  const float* wsf = (const float*)d_in[2];
  const float* w2f = (const float*)d_in[3];

  // ---- meta region (< 512 KB) ----
  int* counts   = (int*)d_ws;
  int* offs     = counts + 8;
  int* cursor   = offs + 16;
  int* tids     = cursor + 8;
  float* tw     = (float*)(tids + NPAIR);
  int* perm     = (int*)(tw + NPAIR);
  float* pw     = (float*)(perm + PADROWS);
  int* pairpos  = (int*)(pw + PADROWS);

  // ---- layout (peak 520.6 MB < proven 579.3 MB floor) ----
  // BIG region (wsh, 268 MB) overlays: w2h1 = slabs 0-1 (67 MB, written by
  // gemm1 dispatches 2-3 which read slabs 4-7); hb2 at +134 MB (written by
  // gemm2 after all of wsh is dead).
  char* base = (char*)d_ws;
  size_t off_xh   = (size_t)512 * 1024;                     // xh:   33.5 MB
  size_t off_hb   = off_xh + (size_t)TTOK * HD * 2;         // hb:   151 MB
  size_t off_w2h0 = off_hb + (size_t)PADROWS * ID * 2;      // w2h0:  67 MB
  size_t off_big  = off_w2h0 + (size_t)NE * HD * 2048 * 2;  // BIG:  268 MB
  size_t need     = off_big + (size_t)NE * 2 * ID * HD * 2; // = 520,617,984
  if (ws_size < need) return;

  _Float16* xh   = (_Float16*)(base + off_xh);
  _Float16* hb   = (_Float16*)(base + off_hb);
  _Float16* w2h0 = (_Float16*)(base + off_w2h0);
  _Float16* wsh  = (_Float16*)(base + off_big);
  _Float16* w2h1 = (_Float16*)(base + off_big);                               // slabs 0-1
  _Float16* hb2  = (_Float16*)(base + off_big + (size_t)NE * HD * 2048 * 2);  // +134 MB

  hipMemsetAsync(counts, 0, 64, stream);

  gate_kernel<<<TTOK / 4, 256, 0, stream>>>(x, gw, counts, tids, tw, xh);
  cvt_ws01_kernel<<<256, 512, 0, stream>>>(wsf, wsh);     // Ws slabs 0-1 (~80 us)
  scan_kernel<<<1, 64, 0, stream>>>(counts, offs, cursor);
  scatter_kernel<<<TTOK / 256, 256, 0, stream>>>(tids, tw, cursor, perm, pw, pairpos);
  padfill_kernel<<<PADROWS / 256, 256, 0, stream>>>(counts, offs, perm);

  // gemm1 pair dispatches; cvt row (y=0) hides next-pair Ws + W2 quarters;
  // y=1..RBMAX covers ALL row-blocks (r12 covered only 64 -> poison rows)
  for (int pid = 0; pid < 4; ++pid)
    gemm1_kernel<<<dim3(32, RBMAX + 1), 512, 0, stream>>>(
        xh, wsh, offs, perm, hb, wsf, w2f, w2h0, w2h1, pid);

  // gemm2: single dispatch, z=2 K-halves
  gemm2_kernel<<<dim3(HD / 256, RBMAX, 2), 512, 0, stream>>>(
      hb, w2h0, w2h1, offs, hb2);

  combine_kernel<<<(TTOK * HD / 8) / 256, 256, 0, stream>>>(
      hb2, pairpos, pw, (float*)d_out);
}

// Round 14
// 1340.265 us; speedup vs baseline: 1.1920x; 1.1920x over previous
//
#include <hip/hip_runtime.h>
#include <hip/hip_fp16.h>
#include <cstdint>
#include <cstddef>

#define TTOK 8192
#define HD   2048
#define ID   4096
#define NE   8
#define NPAIR (TTOK * 2)            // 16384 routed pairs
#define PADROWS 18432               // 16384 + 8*256 worst-case padded rows
#define RBMAX 72                    // PADROWS / 256

typedef _Float16 h8 __attribute__((ext_vector_type(8)));
typedef float    f4 __attribute__((ext_vector_type(4)));

#define VMWAIT(n) asm volatile("s_waitcnt vmcnt(" #n ")" ::: "memory")
#define MEMFENCE  asm volatile("" ::: "memory")
#define BAR()     __builtin_amdgcn_s_barrier()

__device__ __forceinline__ void async_cp16(const void* g, void* l) {
  __builtin_amdgcn_global_load_lds(
      (const __attribute__((address_space(1))) unsigned int*)g,
      (__attribute__((address_space(3))) unsigned int*)l, 16, 0, 0);
}

__device__ __forceinline__ f4 zero4() { f4 z = {0.f, 0.f, 0.f, 0.f}; return z; }

// ---- contiguous fp32->f16 cvt slice (nthr = threads/block of caller) ----
__device__ __forceinline__ void cvt_slice(const float* __restrict__ src,
                                          _Float16* __restrict__ dst,
                                          size_t n, int cb, int ncb, int nthr) {
  size_t stride = (size_t)ncb * nthr * 8;
  for (size_t i = ((size_t)cb * nthr + threadIdx.x) * 8; i < n; i += stride) {
    const float4* s = (const float4*)(src + i);
    float4 a = s[0], b = s[1];
    h8 o;
    o[0] = (_Float16)a.x; o[1] = (_Float16)a.y; o[2] = (_Float16)a.z; o[3] = (_Float16)a.w;
    o[4] = (_Float16)b.x; o[5] = (_Float16)b.y; o[6] = (_Float16)b.z; o[7] = (_Float16)b.w;
    *(h8*)(dst + i) = o;
  }
}

// ---- W2 K-half cvt: w2f[e][h][kh*2048 + ic] -> dst[(e*HD+h)*2048 + ic]
__device__ __forceinline__ void cvt_w2_half(const float* __restrict__ w2f,
                                            _Float16* __restrict__ dst,
                                            int kh, int cb, int ncb, int nthr) {
  const size_t n = (size_t)NE * HD * 2048;
  size_t stride = (size_t)ncb * nthr * 8;
  for (size_t j = ((size_t)cb * nthr + threadIdx.x) * 8; j < n; j += stride) {
    size_t row = j >> 11, ic = j & 2047;
    const float4* s = (const float4*)(w2f + row * ID + (size_t)kh * 2048 + ic);
    float4 a = s[0], b = s[1];
    h8 o;
    o[0] = (_Float16)a.x; o[1] = (_Float16)a.y; o[2] = (_Float16)a.z; o[3] = (_Float16)a.w;
    o[4] = (_Float16)b.x; o[5] = (_Float16)b.y; o[6] = (_Float16)b.z; o[7] = (_Float16)b.w;
    *(h8*)(dst + row * 2048 + ic) = o;
  }
}

// ---- fallback standalone W2-half1 cvt ----
__global__ __launch_bounds__(512) void cvt_w2half_kernel(
    const float* __restrict__ w2f, _Float16* __restrict__ dst, int kh) {
  cvt_w2_half(w2f, dst, kh, blockIdx.x, gridDim.x, 512);
}

// ---- fused gate (blocks 0..2047) + full Ws fp32->f16 cvt (blocks 2048..4095)
//      writes disjoint (counts/tids/tw/xh vs wsh); consumers in later dispatches
__global__ __launch_bounds__(256) void gate_cvt_kernel(
    const float* __restrict__ x, const float* __restrict__ gw,
    int* __restrict__ counts, int* __restrict__ tids, float* __restrict__ tw,
    _Float16* __restrict__ xh,
    const float* __restrict__ wsf, _Float16* __restrict__ wsh) {
  if (blockIdx.x >= 2048) {
    cvt_slice(wsf, wsh, (size_t)NE * 2 * ID * HD, blockIdx.x - 2048, 2048, 256);
    return;
  }
  int lane = threadIdx.x & 63;
  int t = blockIdx.x * 4 + (threadIdx.x >> 6);
  const float* xr = x + (size_t)t * HD;
  _Float16* xhr = xh + (size_t)t * HD;
  float acc[NE];
#pragma unroll
  for (int e = 0; e < NE; e++) acc[e] = 0.f;
  for (int j = lane; j < HD; j += 64) {
    float xv = xr[j];
    xhr[j] = (_Float16)xv;            // fused x -> f16
#pragma unroll
    for (int e = 0; e < NE; e++) acc[e] += xv * gw[e * HD + j];
  }
#pragma unroll
  for (int off = 32; off > 0; off >>= 1) {
#pragma unroll
    for (int e = 0; e < NE; e++) acc[e] += __shfl_xor(acc[e], off, 64);
  }
  if (lane == 0) {
    int e0 = 0; float v0 = acc[0];
#pragma unroll
    for (int e = 1; e < NE; e++) if (acc[e] > v0) { v0 = acc[e]; e0 = e; }
    int e1 = -1; float v1 = -1e30f;
#pragma unroll
    for (int e = 0; e < NE; e++) if (e != e0 && acc[e] > v1) { v1 = acc[e]; e1 = e; }
    float b = __expf(v1 - v0);
    float w0 = 1.f / (1.f + b);
    tids[2 * t] = e0; tids[2 * t + 1] = e1;
    tw[2 * t] = w0;   tw[2 * t + 1] = b * w0;
    atomicAdd(&counts[e0], 1); atomicAdd(&counts[e1], 1);
  }
}

// ---------------- scan: per-expert 256-padded offsets ----------------
__global__ void scan_kernel(const int* __restrict__ counts, int* __restrict__ offs,
                            int* __restrict__ cursor) {
  if (threadIdx.x == 0 && blockIdx.x == 0) {
    int off = 0;
    for (int e = 0; e < NE; e++) {
      offs[e] = off; cursor[e] = off;
      off += ((counts[e] + 255) >> 8) << 8;
    }
    offs[NE] = off;
  }
}

// ---------------- scatter tokens (records token->slot map) ----------------
__global__ void scatter_kernel(const int* __restrict__ tids, const float* __restrict__ tw,
                               int* __restrict__ cursor, int* __restrict__ perm,
                               float* __restrict__ pw, int* __restrict__ pairpos) {
  int t = blockIdx.x * 256 + threadIdx.x;
#pragma unroll
  for (int k = 0; k < 2; k++) {
    int e = tids[2 * t + k];
    int pos = atomicAdd(&cursor[e], 1);
    perm[pos] = t; pw[pos] = tw[2 * t + k];
    pairpos[2 * t + k] = pos;
  }
}

// ---------------- mark padding ----------------
__global__ void padfill_kernel(const int* __restrict__ counts, const int* __restrict__ offs,
                               int* __restrict__ perm) {
  int s = blockIdx.x * 256 + threadIdx.x;
#pragma unroll
  for (int e = 0; e < NE; e++) {
    if (s >= offs[e] + counts[e] && s < offs[e + 1]) perm[s] = -1;
  }
}

// ============================================================================
// r7's PROVEN 8-phase 256x256x64 KLOOP — UNTOUCHED.
// ============================================================================
#define LA(BB, H) ((BB) * 65536 + (H) * 16384)
#define LB(BB, H) ((BB) * 65536 + 32768 + (H) * 16384)
#define RD(boff) (*(const h8*)(smem + (boff)))

#define LOAD_AF(BB, MH) do { \
  af[0][0] = RD(LA(BB,MH) + amoff + 0*2048 + sa0); \
  af[0][1] = RD(LA(BB,MH) + amoff + 0*2048 + sa1); \
  af[1][0] = RD(LA(BB,MH) + amoff + 1*2048 + sa0); \
  af[1][1] = RD(LA(BB,MH) + amoff + 1*2048 + sa1); \
  af[2][0] = RD(LA(BB,MH) + amoff + 2*2048 + sa0); \
  af[2][1] = RD(LA(BB,MH) + amoff + 2*2048 + sa1); \
  af[3][0] = RD(LA(BB,MH) + amoff + 3*2048 + sa0); \
  af[3][1] = RD(LA(BB,MH) + amoff + 3*2048 + sa1); } while (0)

#define LOAD_BFG(BB) do { \
  bfg[0][0] = RD(LB(BB,0) + bnoff + 0*2048 + sa0); \
  bfg[0][1] = RD(LB(BB,0) + bnoff + 0*2048 + sa1); \
  bfg[1][0] = RD(LB(BB,0) + bnoff + 1*2048 + sa0); \
  bfg[1][1] = RD(LB(BB,0) + bnoff + 1*2048 + sa1); } while (0)

#define LOAD_BFU(BB) do { \
  bfu[0][0] = RD(LB(BB,1) + bnoff + 0*2048 + sa0); \
  bfu[0][1] = RD(LB(BB,1) + bnoff + 0*2048 + sa1); \
  bfu[1][0] = RD(LB(BB,1) + bnoff + 1*2048 + sa0); \
  bfu[1][1] = RD(LB(BB,1) + bnoff + 1*2048 + sa1); } while (0)

#define MM(MH,NH,BF,M,N) \
  acc[MH][NH][M][N] = __builtin_amdgcn_mfma_f32_16x16x32_f16(af[M][0], BF[N][0], acc[MH][NH][M][N], 0, 0, 0); \
  acc[MH][NH][M][N] = __builtin_amdgcn_mfma_f32_16x16x32_f16(af[M][1], BF[N][1], acc[MH][NH][M][N], 0, 0, 0);

#define MFMAQ(MH,NH,BF) do { __builtin_amdgcn_s_setprio(1); \
  MM(MH,NH,BF,0,0) MM(MH,NH,BF,0,1) MM(MH,NH,BF,1,0) MM(MH,NH,BF,1,1) \
  MM(MH,NH,BF,2,0) MM(MH,NH,BF,2,1) MM(MH,NH,BF,3,0) MM(MH,NH,BF,3,1) \
  __builtin_amdgcn_s_setprio(0); } while (0)

#define STG(gp, ldsbyte, kt) do { \
  async_cp16(gp[0] + (size_t)(kt) * 64, smem + (ldsbyte) + (wid * 2 + 0) * 1024 + lane * 16); \
  async_cp16(gp[1] + (size_t)(kt) * 64, smem + (ldsbyte) + (wid * 2 + 1) * 1024 + lane * 16); } while (0)

#define ACC_ZERO() do { \
  _Pragma("unroll") for (int mh = 0; mh < 2; mh++) \
  _Pragma("unroll") for (int nh = 0; nh < 2; nh++) \
  _Pragma("unroll") for (int m = 0; m < 4; m++) \
  _Pragma("unroll") for (int n = 0; n < 2; n++) acc[mh][nh][m][n] = zero4(); } while (0)

#define KLOOP(NI) \
  STG(gA[0], LA(0,0), 0); STG(gA[1], LA(0,1), 0); \
  STG(gB[0], LB(0,0), 0); STG(gB[1], LB(0,1), 0); \
  STG(gA[0], LA(1,0), 1); STG(gB[1], LB(1,1), 1); \
  VMWAIT(4); \
  BAR(); \
  for (int i = 0; i < (NI); ++i) { \
    bool last = (i == (NI) - 1); \
    int kt1 = 2 * i + 1, kt2 = 2 * i + 2, kt3 = 2 * i + 3; \
    /* ph1 */ \
    MEMFENCE; LOAD_AF(0,0); LOAD_BFG(0); \
    STG(gA[1], LA(1,1), kt1); STG(gB[0], LB(1,0), kt1); \
    BAR(); MEMFENCE; MFMAQ(0,0,bfg); BAR(); \
    /* ph2 */ \
    MEMFENCE; LOAD_BFU(0); \
    BAR(); MEMFENCE; MFMAQ(0,1,bfu); BAR(); \
    /* ph3 */ \
    MEMFENCE; LOAD_AF(0,1); \
    if (!last) STG(gA[0], LA(0,0), kt2); \
    BAR(); MEMFENCE; MFMAQ(1,1,bfu); BAR(); \
    /* ph4 (no ds_reads: bfg retained from ph1) */ \
    MEMFENCE; \
    if (!last) { STG(gB[1], LB(0,1), kt2); VMWAIT(4); } else { VMWAIT(0); } \
    BAR(); MEMFENCE; MFMAQ(1,0,bfg); BAR(); \
    /* ph5 */ \
    MEMFENCE; LOAD_AF(1,0); LOAD_BFG(1); \
    if (!last) { STG(gA[1], LA(0,1), kt2); STG(gB[0], LB(0,0), kt2); } \
    BAR(); MEMFENCE; MFMAQ(0,0,bfg); BAR(); \
    /* ph6 */ \
    MEMFENCE; LOAD_BFU(1); \
    BAR(); MEMFENCE; MFMAQ(0,1,bfu); BAR(); \
    /* ph7 */ \
    MEMFENCE; LOAD_AF(1,1); \
    if (!last) STG(gA[0], LA(1,0), kt3); \
    BAR(); MEMFENCE; MFMAQ(1,1,bfu); BAR(); \
    /* ph8 (no ds_reads) */ \
    MEMFENCE; \
    if (!last) { STG(gB[1], LB(1,1), kt3); VMWAIT(4); } \
    BAR(); MEMFENCE; MFMAQ(1,0,bfg); BAR(); \
  }

// expert lookup from 256-aligned offsets (row0 = global row-block * 256)
__device__ __forceinline__ int expert_of(const int* offs, int row0) {
  int e = 0;
#pragma unroll
  for (int k = 1; k < NE; k++) if (offs[k] <= row0) e = k;
  return e;
}

// ---- gemm1: single dispatch, y<RBMAX gemm rows; tail rows = hidden W2 cvt:
//      y in [RBMAX, RBMAX+8)    -> w2h0 (always)
//      y in [RBMAX+8, RBMAX+16) -> w2h1 (fast path only: own storage region)
__global__ __launch_bounds__(512, 2) void gemm1_kernel(
    const _Float16* __restrict__ xh, const _Float16* __restrict__ wsh,
    const int* __restrict__ offs, const int* __restrict__ perm,
    _Float16* __restrict__ hb,
    const float* __restrict__ w2f, _Float16* __restrict__ w2h0,
    _Float16* __restrict__ w2h1t) {
  int bx = blockIdx.x, gyy = blockIdx.y;
  if (gyy >= RBMAX) {
    int s = gyy - RBMAX;               // 0..15
    if (s < 8) cvt_w2_half(w2f, w2h0, 0, s * 32 + bx, 256, 512);
    else       cvt_w2_half(w2f, w2h1t, 1, (s - 8) * 32 + bx, 256, 512);
    return;
  }
  int row0 = gyy << 8;
  if (row0 >= offs[NE]) return;
  int e = expert_of(offs, row0);
  int n0 = bx << 7;   // 128 h-cols

  __shared__ char smem[131072];
  int tid = threadIdx.x, lane = tid & 63, wid = tid >> 6;
  int wm = wid >> 2, wn = wid & 3;
  int lr = lane & 15, ks = lane >> 4;
  int sa0 = lr * 128 + (((ks)     ^ (lr & 7)) << 4);
  int sa1 = lr * 128 + (((ks + 4) ^ (lr & 7)) << 4);
  int amoff = wm * 8192;
  int bnoff = wn * 4096;

  int srow = wid * 16 + (lane >> 3);
  int scol = ((lane & 7) ^ (lane >> 3)) * 8;   // pre-swizzled source chunk
  const _Float16* gA[2][2]; const _Float16* gB[2][2];
#pragma unroll
  for (int h = 0; h < 2; h++)
#pragma unroll
    for (int j = 0; j < 2; j++) {
      int r = row0 + h * 128 + srow + j * 8;
      int pv = perm[r]; if (pv < 0) pv = 0;
      gA[h][j] = xh + (size_t)pv * HD + scol;
      gB[h][j] = wsh + ((size_t)e * 2 * ID + (size_t)h * ID + n0 + srow + j * 8) * HD + scol;
    }

  f4 acc[2][2][4][2];
  h8 af[4][2], bfg[2][2], bfu[2][2];
  ACC_ZERO();

  KLOOP(16)   // HD / 128

  // epilogue: silu(g)*u fused in-register (nh0 = g, nh1 = u, same h-col)
#pragma unroll
  for (int mh = 0; mh < 2; mh++)
#pragma unroll
    for (int m = 0; m < 4; m++)
#pragma unroll
      for (int n = 0; n < 2; n++)
#pragma unroll
        for (int r = 0; r < 4; r++) {
          float g = acc[mh][0][m][n][r], u = acc[mh][1][m][n][r];
          float hv = g / (1.f + __expf(-g)) * u;
          int row = row0 + mh * 128 + wm * 64 + m * 16 + ks * 4 + r;
          int col = n0 + wn * 32 + n * 16 + lr;
          __builtin_nontemporal_store((_Float16)hv, hb + (size_t)row * ID + col);
        }
}

// ---- gemm2 (K-split, z=2 single dispatch): hb2[kh] = h[:,kh-half] @ W2half^T ----
__global__ __launch_bounds__(512, 2) void gemm2_kernel(
    const _Float16* __restrict__ hb, const _Float16* __restrict__ w2h0,
    const _Float16* __restrict__ w2h1, const int* __restrict__ offs,
    _Float16* __restrict__ hb2) {
  int bx = blockIdx.x, gyy = blockIdx.y;
  int row0 = gyy << 8;
  if (row0 >= offs[NE]) return;
  int e = expert_of(offs, row0);
  int n0 = bx << 8;                  // 256 out-cols
  int kh = blockIdx.z;               // K half
  const _Float16* w2hk = kh ? w2h1 : w2h0;
  size_t k0 = (size_t)kh * 2048;

  __shared__ char smem[131072];
  int tid = threadIdx.x, lane = tid & 63, wid = tid >> 6;
  int wm = wid >> 2, wn = wid & 3;
  int lr = lane & 15, ks = lane >> 4;
  int sa0 = lr * 128 + (((ks)     ^ (lr & 7)) << 4);
  int sa1 = lr * 128 + (((ks + 4) ^ (lr & 7)) << 4);
  int amoff = wm * 8192;
  int bnoff = wn * 4096;

  int srow = wid * 16 + (lane >> 3);
  int scol = ((lane & 7) ^ (lane >> 3)) * 8;
  const _Float16* gA[2][2]; const _Float16* gB[2][2];
#pragma unroll
  for (int h = 0; h < 2; h++)
#pragma unroll
    for (int j = 0; j < 2; j++) {
      gA[h][j] = hb + ((size_t)(row0 + h * 128 + srow + j * 8)) * ID + k0 + scol;
      gB[h][j] = w2hk + ((size_t)e * HD + n0 + h * 128 + srow + j * 8) * 2048 + scol;
    }

  f4 acc[2][2][4][2];
  h8 af[4][2], bfg[2][2], bfu[2][2];
  ACC_ZERO();

  KLOOP(16)   // 2048 / 128

#pragma unroll
  for (int mh = 0; mh < 2; mh++)
#pragma unroll
    for (int nh = 0; nh < 2; nh++)
#pragma unroll
      for (int m = 0; m < 4; m++)
#pragma unroll
        for (int n = 0; n < 2; n++)
#pragma unroll
          for (int r = 0; r < 4; r++) {
            int row = row0 + mh * 128 + wm * 64 + m * 16 + ks * 4 + r;
            int col = n0 + nh * 128 + wn * 32 + n * 16 + lr;
            hb2[(size_t)kh * PADROWS * HD + (size_t)row * HD + col] =
                (_Float16)acc[mh][nh][m][n][r];
          }
}

// ---- combine: out[t] = pw[p0]*(A0+A1)[p0] + pw[p1]*(B0+B1)[p1], fixed order ----
__global__ __launch_bounds__(256) void combine_kernel(
    const _Float16* __restrict__ hb2, const int* __restrict__ pairpos,
    const float* __restrict__ pw, float* __restrict__ out) {
  int i = blockIdx.x * 256 + threadIdx.x;   // T*HD/8 threads
  int t = i >> 8, g = (i & 255) * 8;
  int p0 = pairpos[2 * t], p1 = pairpos[2 * t + 1];
  float w0 = pw[p0], w1 = pw[p1];
  const _Float16* hb2b = hb2 + (size_t)PADROWS * HD;
  h8 a0 = *(const h8*)(hb2  + (size_t)p0 * HD + g);
  h8 a1 = *(const h8*)(hb2b + (size_t)p0 * HD + g);
  h8 b0 = *(const h8*)(hb2  + (size_t)p1 * HD + g);
  h8 b1 = *(const h8*)(hb2b + (size_t)p1 * HD + g);
  f4 o0, o1;
#pragma unroll
  for (int j = 0; j < 4; j++)
    o0[j] = w0 * ((float)a0[j] + (float)a1[j]) + w1 * ((float)b0[j] + (float)b1[j]);
#pragma unroll
  for (int j = 0; j < 4; j++)
    o1[j] = w0 * ((float)a0[j + 4] + (float)a1[j + 4]) + w1 * ((float)b0[j + 4] + (float)b1[j + 4]);
  __builtin_nontemporal_store(o0, (f4*)(out + (size_t)t * HD + g));
  __builtin_nontemporal_store(o1, (f4*)(out + (size_t)t * HD + g + 4));
}

// ---------------- host launcher ----------------
extern "C" void kernel_launch(void* const* d_in, const int* in_sizes, int n_in,
                              void* d_out, int out_size, void* d_ws, size_t ws_size,
                              hipStream_t stream) {
  const float* x   = (const float*)d_in[0];
  const float* gw  = (const float*)d_in[1];
  const float* wsf = (const float*)d_in[2];
  const float* w2f = (const float*)d_in[3];

  // ---- meta region (< 512 KB) ----
  int* counts   = (int*)d_ws;
  int* offs     = counts + 8;
  int* cursor   = offs + 16;
  int* tids     = cursor + 8;
  float* tw     = (float*)(tids + NPAIR);
  int* perm     = (int*)(tw + NPAIR);
  float* pw     = (float*)(perm + PADROWS);
  int* pairpos  = (int*)(pw + PADROWS);

  char* base = (char*)d_ws;
  size_t off_xh   = (size_t)512 * 1024;                     // xh:   33.5 MB
  size_t off_hb   = off_xh + (size_t)TTOK * HD * 2;         // hb:   151 MB
  size_t off_w2h0 = off_hb + (size_t)PADROWS * ID * 2;      // w2h0:  67 MB
  size_t w2half   = (size_t)NE * HD * 2048 * 2;             // 67.1 MB

  // FAST layout: w2h1 gets its own region (written during gemm1 tail):
  //   meta|xh|hb|w2h0|w2h1|wsh ; hb2 overlays wsh (dead in gemm2). 587.7 MB.
  size_t f_off_w2h1 = off_w2h0 + w2half;
  size_t f_off_wsh  = f_off_w2h1 + w2half;
  size_t need_fast  = f_off_wsh + (size_t)NE * 2 * ID * HD * 2;  // 587,726,848
  // FALLBACK (r11-proven): w2h1 aliases wsh slabs 0-1, standalone cvt after
  // gemm1; hb2 at wsh+134.2 MB. Peak use 537.3 MB (< proven 579.3 floor).
  size_t b_off_wsh  = off_w2h0 + w2half;
  size_t need_fb    = b_off_wsh + (size_t)NE * 2 * ID * HD * 2;  // 520.6 MB check
  if (ws_size < need_fb) return;

  bool fast = (ws_size >= need_fast);
  size_t off_wsh = fast ? f_off_wsh : b_off_wsh;

  _Float16* xh   = (_Float16*)(base + off_xh);
  _Float16* hb   = (_Float16*)(base + off_hb);
  _Float16* w2h0 = (_Float16*)(base + off_w2h0);
  _Float16* wsh  = (_Float16*)(base + off_wsh);
  _Float16* w2h1 = fast ? (_Float16*)(base + f_off_w2h1)
                        : (_Float16*)(base + off_wsh);          // alias slabs 0-1
  _Float16* hb2  = fast ? (_Float16*)(base + off_wsh)           // wsh dead in gemm2
                        : (_Float16*)(base + off_wsh + 2 * w2half);

  hipMemsetAsync(counts, 0, 64, stream);

  // fused gate + full Ws cvt (one BW-bound dispatch)
  gate_cvt_kernel<<<4096, 256, 0, stream>>>(x, gw, counts, tids, tw, xh, wsf, wsh);
  scan_kernel<<<1, 64, 0, stream>>>(counts, offs, cursor);
  scatter_kernel<<<TTOK / 256, 256, 0, stream>>>(tids, tw, cursor, perm, pw, pairpos);
  padfill_kernel<<<PADROWS / 256, 256, 0, stream>>>(counts, offs, perm);

  // gemm1 + hidden W2 cvt tail (w2h0 always; w2h1 too when fast layout fits)
  gemm1_kernel<<<dim3(32, RBMAX + (fast ? 16 : 8)), 512, 0, stream>>>(
      xh, wsh, offs, perm, hb, w2f, w2h0, w2h1);

  if (!fast)  // w2h1 aliases wsh: convert only after gemm1 is done with it
    cvt_w2half_kernel<<<512, 512, 0, stream>>>(w2f, w2h1, 1);

  // gemm2: single dispatch, z=2 K-halves
  gemm2_kernel<<<dim3(HD / 256, RBMAX, 2), 512, 0, stream>>>(
      hb, w2h0, w2h1, offs, hb2);

  combine_kernel<<<(TTOK * HD / 8) / 256, 256, 0, stream>>>(
      hb2, pairpos, pw, (float*)d_out);
}